// Round 1
// baseline (327.247 us; speedup 1.0000x reference)
//
#include <hip/hip_runtime.h>
#include <hip/hip_bf16.h>
#include <stdint.h>

typedef __attribute__((ext_vector_type(8))) short bf16x8;
typedef __attribute__((ext_vector_type(4))) float f32x4;

#define N_PIX 4096
#define C_CH  256
#define SCALE_LOG2E (0.0625f * 1.4426950408889634f)  // c^-0.5 * log2(e)

__device__ __forceinline__ unsigned short f2bf(float f) {
    unsigned int u = __float_as_uint(f);
    unsigned int r = (u + 0x7FFFu + ((u >> 16) & 1u)) >> 16;  // RNE
    return (unsigned short)r;
}

// ---------------- kernel 1: groupnorm stats -> per-channel a, bb ----------
__global__ void gn_stats_kernel(const float* __restrict__ x,
                                const float* __restrict__ gn_w,
                                const float* __restrict__ gn_b,
                                float* __restrict__ a_out,   // [4][256]
                                float* __restrict__ b_out) { // [4][256]
    int bg = blockIdx.x;            // 0..127
    int b = bg >> 5, g = bg & 31;
    const float* base = x + ((size_t)(b * C_CH + g * 8)) * N_PIX;
    float s1 = 0.f, s2 = 0.f;
    for (int i = threadIdx.x; i < 8 * N_PIX; i += 256) {
        float v = base[i];
        s1 += v; s2 += v * v;
    }
    __shared__ float r1[256], r2[256];
    r1[threadIdx.x] = s1; r2[threadIdx.x] = s2;
    __syncthreads();
    for (int off = 128; off > 0; off >>= 1) {
        if (threadIdx.x < off) {
            r1[threadIdx.x] += r1[threadIdx.x + off];
            r2[threadIdx.x] += r2[threadIdx.x + off];
        }
        __syncthreads();
    }
    if (threadIdx.x < 8) {
        float mean = r1[0] * (1.f / 32768.f);
        float var  = r2[0] * (1.f / 32768.f) - mean * mean;
        float rstd = rsqrtf(var + 1e-5f);
        int c = g * 8 + threadIdx.x;
        float A = rstd * gn_w[c];
        a_out[b * C_CH + c] = A;
        b_out[b * C_CH + c] = gn_b[c] - mean * A;
    }
}

// ---------------- kernel 2: cast weights to bf16 --------------------------
__global__ void cast_w_kernel(const float* __restrict__ qkv_w,
                              const float* __restrict__ out_w,
                              unsigned short* __restrict__ wq,   // [768][256]
                              unsigned short* __restrict__ w2) { // [256][256]
    int i = blockIdx.x * 256 + threadIdx.x;
    if (i < 768 * 256) wq[i] = f2bf(qkv_w[i]);
    if (i < 256 * 256) w2[i] = f2bf(out_w[i]);
}

// ---------------- kernel 3: fused norm + QKV GEMM --------------------------
// out[p][o] = sum_c (a[c]*x[c][p]+bb[c]) * W[o][c] + qkv_b[o]
// och 0 -> q_seq[b][p][c] (pre-scaled by scale*log2e), 1 -> k_seq, 2 -> vT[b][c][p]
__global__ __launch_bounds__(256)
void qkv_gemm_kernel(const float* __restrict__ x,
                     const float* __restrict__ a_arr,
                     const float* __restrict__ bb_arr,
                     const unsigned short* __restrict__ wq,
                     const float* __restrict__ qkv_b,
                     unsigned short* __restrict__ q_seq,
                     unsigned short* __restrict__ k_seq,
                     unsigned short* __restrict__ vT) {
    int pb   = blockIdx.x;          // 0..63
    int och  = blockIdx.y;          // 0..2
    int b    = blockIdx.z;          // 0..3
    int wave = threadIdx.x >> 6;
    int lane = threadIdx.x & 63;
    int lo = lane & 15, hi = lane >> 4;
    int prow = pb * 64 + wave * 16 + lo;
    const float* xb = x + (size_t)b * C_CH * N_PIX;
    const float* av = a_arr + b * C_CH;
    const float* bv = bb_arr + b * C_CH;

    f32x4 acc[16];
#pragma unroll
    for (int t = 0; t < 16; t++) acc[t] = (f32x4)0.f;

#pragma unroll
    for (int ks = 0; ks < 8; ks++) {
        int c0 = ks * 32 + hi * 8;
        bf16x8 afrag;
#pragma unroll
        for (int i = 0; i < 8; i++) {
            float xv = xb[(size_t)(c0 + i) * N_PIX + prow];
            float v  = fmaf(av[c0 + i], xv, bv[c0 + i]);
            afrag[i] = (short)f2bf(v);
        }
#pragma unroll
        for (int t = 0; t < 16; t++) {
            int orow = och * 256 + t * 16 + lo;
            bf16x8 bfrag = *(const bf16x8*)(wq + (size_t)orow * 256 + c0);
            acc[t] = __builtin_amdgcn_mfma_f32_16x16x32_bf16(afrag, bfrag, acc[t], 0, 0, 0);
        }
    }

    int p_base = pb * 64 + wave * 16 + hi * 4;
#pragma unroll
    for (int t = 0; t < 16; t++) {
        int o = och * 256 + t * 16 + lo;
        float bias = qkv_b[o];
        if (och == 2) {
            ushort4 pk;
            pk.x = f2bf(acc[t][0] + bias);
            pk.y = f2bf(acc[t][1] + bias);
            pk.z = f2bf(acc[t][2] + bias);
            pk.w = f2bf(acc[t][3] + bias);
            *(ushort4*)(vT + ((size_t)(b * C_CH + (o - 512))) * N_PIX + p_base) = pk;
        } else {
            float sc = (och == 0) ? SCALE_LOG2E : 1.f;
            unsigned short* dst = (och == 0 ? q_seq : k_seq) + (size_t)b * N_PIX * C_CH;
            int cc = o - och * 256;
#pragma unroll
            for (int r = 0; r < 4; r++)
                dst[(size_t)(p_base + r) * 256 + cc] = f2bf((acc[t][r] + bias) * sc);
        }
    }
}

// ---------------- kernel 4: flash attention + fused out-proj + residual ----
// block: 64 Q rows (4 waves x 16), KV tile 64. LDS: Kt 32KB | Vt 32KB, P/O overlay Kt.
__global__ __launch_bounds__(256)
void attn_kernel(const unsigned short* __restrict__ q_seq,
                 const unsigned short* __restrict__ k_seq,
                 const unsigned short* __restrict__ vT,
                 const unsigned short* __restrict__ w2,
                 const float* __restrict__ out_b,
                 const float* __restrict__ x,
                 float* __restrict__ y) {
    extern __shared__ char lds[];
    char* Kt = lds;             // 64 rows x 512B, swizzled
    char* Vt = lds + 32768;     // 256 rows x 128B, swizzled

    int bid  = blockIdx.x;
    int work = (bid & 7) * 32 + (bid >> 3);   // XCD-aware swizzle (256 wgs, 8 XCDs)
    int b  = work >> 6;
    int pb = work & 63;
    int tid = threadIdx.x;
    int wave = tid >> 6, lane = tid & 63, lo = lane & 15, hi = lane >> 4;
    int swz = (lo & 7) << 4;                  // per-lane XOR for row = *16 + lo
    int p0 = pb * 64 + wave * 16;

    const unsigned short* qb = q_seq + (size_t)b * N_PIX * C_CH;
    const unsigned short* kb = k_seq + (size_t)b * N_PIX * C_CH;
    const unsigned short* vb = vT   + (size_t)b * C_CH * N_PIX;

    bf16x8 qfrag[8];
#pragma unroll
    for (int ks = 0; ks < 8; ks++)
        qfrag[ks] = *(const bf16x8*)(qb + (size_t)(p0 + lo) * 256 + ks * 32 + hi * 8);

    f32x4 oacc[16];
#pragma unroll
    for (int t = 0; t < 16; t++) oacc[t] = (f32x4)0.f;
    float m[4]    = {-1e30f, -1e30f, -1e30f, -1e30f};
    float lsum[4] = {0.f, 0.f, 0.f, 0.f};

    char* Pw = lds + wave * 2048;             // 16 x 128B, overlays Kt (sync-guarded)

    for (int j0 = 0; j0 < N_PIX; j0 += 64) {
        __syncthreads();   // everyone done with previous Kt(P)/Vt
        // stage K tile: 64 rows x 512B
        {
            int r  = tid >> 5;
            int cb = (tid & 31) * 16;
#pragma unroll
            for (int pass = 0; pass < 8; pass++) {
                int row = pass * 8 + r;
                uint4 v = *(const uint4*)((const char*)(kb + (size_t)(j0 + row) * 256) + cb);
                *(uint4*)(Kt + row * 512 + (cb ^ ((row & 7) << 4))) = v;
            }
            // stage V tile: 256 rows x 128B (vT layout [c][n])
            int vr  = tid >> 3;
            int vcb = (tid & 7) * 16;
#pragma unroll
            for (int pass = 0; pass < 8; pass++) {
                int row = pass * 32 + vr;
                uint4 v = *(const uint4*)((const char*)(vb + (size_t)row * N_PIX + j0) + vcb);
                *(uint4*)(Vt + row * 128 + (vcb ^ ((row & 7) << 4))) = v;
            }
        }
        __syncthreads();

        // QK^T : S strip 16x64 per wave (Q pre-scaled by scale*log2e)
        f32x4 s[4];
#pragma unroll
        for (int t = 0; t < 4; t++) s[t] = (f32x4)0.f;
#pragma unroll
        for (int ks = 0; ks < 8; ks++) {
#pragma unroll
            for (int jt = 0; jt < 4; jt++) {
                int row = jt * 16 + lo;
                bf16x8 kf = *(const bf16x8*)(Kt + row * 512 + ((ks * 64 + hi * 16) ^ swz));
                s[jt] = __builtin_amdgcn_mfma_f32_16x16x32_bf16(qfrag[ks], kf, s[jt], 0, 0, 0);
            }
        }

        // online softmax (rows: hi*4+r, cols: jt*16+lo)
        float alpha[4];
#pragma unroll
        for (int r = 0; r < 4; r++) {
            float mx = fmaxf(fmaxf(s[0][r], s[1][r]), fmaxf(s[2][r], s[3][r]));
#pragma unroll
            for (int off = 1; off < 16; off <<= 1)
                mx = fmaxf(mx, __shfl_xor(mx, off, 64));
            float mn = fmaxf(m[r], mx);
            alpha[r] = __builtin_amdgcn_exp2f(m[r] - mn);
            m[r] = mn;
        }
        float psum[4] = {0.f, 0.f, 0.f, 0.f};
#pragma unroll
        for (int jt = 0; jt < 4; jt++) {
#pragma unroll
            for (int r = 0; r < 4; r++) {
                float p = __builtin_amdgcn_exp2f(s[jt][r] - m[r]);
                s[jt][r] = p;
                psum[r] += p;
            }
        }
#pragma unroll
        for (int r = 0; r < 4; r++) {
#pragma unroll
            for (int off = 1; off < 16; off <<= 1)
                psum[r] += __shfl_xor(psum[r], off, 64);
            lsum[r] = lsum[r] * alpha[r] + psum[r];
        }
#pragma unroll
        for (int t = 0; t < 16; t++) {
#pragma unroll
            for (int r = 0; r < 4; r++) oacc[t][r] *= alpha[r];
        }

        __syncthreads();   // all waves done reading Kt -> safe to write P over it
#pragma unroll
        for (int jt = 0; jt < 4; jt++) {
#pragma unroll
            for (int r = 0; r < 4; r++) {
                int row = hi * 4 + r;
                int cbyte = (jt * 16 + lo) * 2;
                *(unsigned short*)(Pw + row * 128 + (cbyte ^ ((row & 7) << 4))) = f2bf(s[jt][r]);
            }
        }

        // PV: oacc[ct] += P(16x64) * V(64x16ct)
#pragma unroll
        for (int ksv = 0; ksv < 2; ksv++) {
            bf16x8 pf = *(const bf16x8*)(Pw + lo * 128 + ((ksv * 64 + hi * 16) ^ swz));
#pragma unroll
            for (int ct = 0; ct < 16; ct++) {
                int vrow = ct * 16 + lo;
                bf16x8 vf = *(const bf16x8*)(Vt + vrow * 128 + ((ksv * 64 + hi * 16) ^ swz));
                oacc[ct] = __builtin_amdgcn_mfma_f32_16x16x32_bf16(pf, vf, oacc[ct], 0, 0, 0);
            }
        }
    }

    // ---- epilogue: normalize, out-proj (o = O * w2^T + out_b), + residual ----
    float rl[4];
#pragma unroll
    for (int r = 0; r < 4; r++) rl[r] = 1.f / lsum[r];

    __syncthreads();                     // everyone done with LDS -> reuse for O strips
    char* Ow = lds + wave * 8192;        // 16 rows x 512B, swizzled
#pragma unroll
    for (int ct = 0; ct < 16; ct++) {
#pragma unroll
        for (int r = 0; r < 4; r++) {
            int row = hi * 4 + r;
            int cbyte = (ct * 16 + lo) * 2;
            *(unsigned short*)(Ow + row * 512 + (cbyte ^ ((row & 7) << 4))) = f2bf(oacc[ct][r] * rl[r]);
        }
    }
    // own-wave LDS read-after-write: compiler inserts lgkmcnt waits

    f32x4 acc2[16];
#pragma unroll
    for (int t = 0; t < 16; t++) acc2[t] = (f32x4)0.f;
#pragma unroll
    for (int ks = 0; ks < 8; ks++) {
        bf16x8 of = *(const bf16x8*)(Ow + lo * 512 + ((ks * 64 + hi * 16) ^ swz));
#pragma unroll
        for (int ot = 0; ot < 16; ot++) {
            bf16x8 wf = *(const bf16x8*)(w2 + (size_t)(ot * 16 + lo) * 256 + ks * 32 + hi * 8);
            acc2[ot] = __builtin_amdgcn_mfma_f32_16x16x32_bf16(of, wf, acc2[ot], 0, 0, 0);
        }
    }

    int p_base = p0 + hi * 4;
#pragma unroll
    for (int ot = 0; ot < 16; ot++) {
        int o = ot * 16 + lo;
        float bias = out_b[o];
        size_t off = ((size_t)(b * C_CH + o)) * N_PIX + p_base;
        f32x4 xv = *(const f32x4*)(x + off);
        f32x4 outv;
#pragma unroll
        for (int r = 0; r < 4; r++) outv[r] = acc2[ot][r] + bias + xv[r];
        *(f32x4*)(y + off) = outv;
    }
}

// ---------------- launch ---------------------------------------------------
extern "C" void kernel_launch(void* const* d_in, const int* in_sizes, int n_in,
                              void* d_out, int out_size, void* d_ws, size_t ws_size,
                              hipStream_t stream) {
    const float* x     = (const float*)d_in[0];
    const float* gn_w  = (const float*)d_in[1];
    const float* gn_b  = (const float*)d_in[2];
    const float* qkv_w = (const float*)d_in[3];
    const float* qkv_b = (const float*)d_in[4];
    const float* out_w = (const float*)d_in[5];
    const float* out_b = (const float*)d_in[6];
    float* y = (float*)d_out;
    char* ws = (char*)d_ws;

    // workspace layout (~24.6 MB total)
    float* a_arr  = (float*)(ws);                    //  4KB
    float* bb_arr = (float*)(ws + 4096);             //  4KB
    unsigned short* wq    = (unsigned short*)(ws + 8192);      // 384KB
    unsigned short* w2    = (unsigned short*)(ws + 401408);    // 128KB
    unsigned short* q_seq = (unsigned short*)(ws + 532480);    // 8MB
    unsigned short* k_seq = (unsigned short*)(ws + 532480 + 8388608);
    unsigned short* vT    = (unsigned short*)(ws + 532480 + 2 * 8388608);

    gn_stats_kernel<<<128, 256, 0, stream>>>(x, gn_w, gn_b, a_arr, bb_arr);
    cast_w_kernel<<<768, 256, 0, stream>>>(qkv_w, out_w, wq, w2);
    qkv_gemm_kernel<<<dim3(64, 3, 4), 256, 0, stream>>>(x, a_arr, bb_arr, wq, qkv_b,
                                                        q_seq, k_seq, vT);
    attn_kernel<<<256, 256, 65536, stream>>>(q_seq, k_seq, vT, w2, out_b, x, y);
}